// Round 12
// baseline (2691.618 us; speedup 1.0000x reference)
//
#include <hip/hip_runtime.h>

// LSTM: B=128, T=512, I=64, H=512, O=1, fp32 in/out.
// R11 = R10 (LDS-staged quarters, champion) + two changes:
//  (1) fire-and-forget publish: data stores -> flag store with NO ack wait;
//      flag/data race closed by 4-bit epoch tags embedded in each 16B granule
//      (hi-plane tag bits compensated via the lo-plane correction, lo-plane
//      tag bits cost 2^-17|h| — R8/R9-proven). Consumer: flag poll (cheap)
//      -> quarter load -> tag validate -> rare retry.
//  (2) projection atomics: per-jg planes part[8][B][T] (4-way contention
//      instead of 32-way on shared lines); reduce_out sums 8 planes.

#define B_ 128
#define T_ 512
#define I_ 64
#define H_ 512

typedef __attribute__((ext_vector_type(8))) short short8;   // 8 bf16
typedef __attribute__((ext_vector_type(4))) float f32x4;
typedef __attribute__((ext_vector_type(4))) unsigned u32x4;

__device__ inline unsigned f2bf_u(float f) {
  union { float f; unsigned u; } v; v.f = f;
  return (v.u + 0x7fffu + ((v.u >> 16) & 1u)) >> 16;  // RNE
}
__device__ inline float bf2f(unsigned s) {
  union { unsigned u; float f; } v; v.u = s << 16; return v.f;
}
__device__ inline float sigm(float x) { return 1.0f / (1.0f + __expf(-x)); }
__device__ inline float tanh_(float x) { return 1.0f - 2.0f / (1.0f + __expf(2.0f * x)); }

#define WAITV(N)                                        \
  asm volatile("s_waitcnt vmcnt(" #N ")" ::: "memory"); \
  __builtin_amdgcn_sched_barrier(0)

// coherent 16B load at L3 point
#define HLOADQ(dst, base, OFF)                                            \
  asm volatile("global_load_dwordx4 %0, %1, off offset:" #OFF " sc0 sc1"  \
               : "=v"(dst) : "v"(base))

// x: read-only input, normal cached path
#define XLOADQ(dst, base, OFF)                                            \
  asm volatile("global_load_dwordx4 %0, %1, off offset:" #OFF             \
               : "=v"(dst) : "v"(base))

// coherent 8B store at L3 point (4 lanes = contiguous 32B)
#define HSTORED2(base, v64)                                               \
  asm volatile("global_store_dwordx2 %0, %1, off sc0 sc1"                 \
               :: "v"(base), "v"(v64) : "memory")

__global__ __launch_bounds__(256, 1) void lstm_kernel(
    const float* __restrict__ x,    // [B,T,I]
    const float* __restrict__ Wih,  // [4H,I]
    const float* __restrict__ Whh,  // [4H,H]
    const float* __restrict__ bih,  // [4H]
    const float* __restrict__ bhh,  // [4H]
    const float* __restrict__ Who,  // [1,H]
    float* __restrict__ part,       // [8 jg][B][T] fp32 partials (atomicAdd)
    unsigned short* __restrict__ hbuf,  // 2 bufs x (hi[B][H], lo[B][H]) bf16
    unsigned* __restrict__ flags)       // 8 bg x 32 per-wave flags
{
  const int bid = blockIdx.x;
  const int jg = bid >> 3;      // 0..7  hidden group (64 j)
  const int bg = bid & 7;       // 0..7  batch group (16 b)
  const int tid = threadIdx.x;
  const int w = tid >> 6;       // wave 0..3
  const int l = tid & 63;
  const int l16 = l & 15;
  const int lk = l >> 4;        // 0..3
  const int b = bg * 16 + l16;

  // ---- resident weights: bf16 A-frags, 4 M-tiles/wave ----
  short8 a_hh[4][16], a_ih[4][2];
  float bias[4][4], who[4];
#pragma unroll
  for (int m = 0; m < 4; ++m) {
    const int rowA = w * 64 + m * 16 + l16;                    // WG row = jl*4+gate
    const int grow = (rowA & 3) * 512 + jg * 64 + (rowA >> 2); // global gate row
#pragma unroll
    for (int kt = 0; kt < 16; ++kt) {
      const float* p = Whh + (size_t)grow * H_ + kt * 32 + lk * 8;
      short8 s;
#pragma unroll
      for (int e = 0; e < 8; ++e) s[e] = (short)f2bf_u(p[e]);
      a_hh[m][kt] = s;
    }
#pragma unroll
    for (int kt = 0; kt < 2; ++kt) {
      const float* p = Wih + (size_t)grow * I_ + kt * 32 + lk * 8;
      short8 s;
#pragma unroll
      for (int e = 0; e < 8; ++e) s[e] = (short)f2bf_u(p[e]);
      a_ih[m][kt] = s;
    }
    const int jm = jg * 64 + w * 16 + m * 4 + lk;
#pragma unroll
    for (int g = 0; g < 4; ++g) bias[m][g] = bih[g * 512 + jm] + bhh[g * 512 + jm];
    who[m] = Who[jm];
  }

  // LDS h-tile: [parity][plane][b][512 j], XOR-swizzled 16B granules (R10).
  __shared__ unsigned short hlds[2][2][16][512];   // 64 KiB
#define HOFS(pl, bb, kt) (((((pl) * 16 + (bb)) * 512) + (kt) * 32 + lk * 8) ^ (((bb) & 7) << 3))

  unsigned short* const hb0 = hbuf;
  unsigned short* const hb1 = hbuf + 2 * B_ * H_;
  unsigned* const fbase = flags + (size_t)bg * 32;
  unsigned* const myflag = fbase + (jg * 4 + w);
  const float* const xrow = x + (size_t)b * (T_ * I_);

  float c[4] = {0.f, 0.f, 0.f, 0.f};
  f32x4 xf0, xf1, xf2, xf3;
  {
    const float* xb = xrow + lk * 8;   // t = 0
    XLOADQ(xf0, xb, 0);   XLOADQ(xf1, xb, 16);
    XLOADQ(xf2, xb, 128); XLOADQ(xf3, xb, 144);
    WAITV(0);
  }

  for (int t = 0; t < T_; ++t) {
    const int pr = t & 1;
    const unsigned short* hp = pr ? hb1 : hb0;   // slot holding h(t-1)
    unsigned short* hn       = pr ? hb0 : hb1;   // slot for h(t)
    unsigned short* const hldsF = &hlds[pr][0][0][0];

    // x(t) regs ready (4 oldest vmem ops = x loads); own publish stores,
    // flag and atomic from step t-1 may still be in flight.
    WAITV(4);

    f32x4 acc[4][2];
#pragma unroll
    for (int m = 0; m < 4; ++m) {
      acc[m][0] = (f32x4){0.f, 0.f, 0.f, 0.f};
      acc[m][1] = (f32x4){0.f, 0.f, 0.f, 0.f};
    }

    // ---- x projection from prefetched regs (pure VALU+MFMA) ----
#pragma unroll
    for (int kt = 0; kt < 2; ++kt) {
      f32x4 va = kt ? xf2 : xf0;
      f32x4 vb = kt ? xf3 : xf1;
      float v[8] = {va[0], va[1], va[2], va[3], vb[0], vb[1], vb[2], vb[3]};
      short8 xhi, xlo;
#pragma unroll
      for (int e = 0; e < 8; ++e) {
        unsigned hb = f2bf_u(v[e]);
        xhi[e] = (short)hb;
        xlo[e] = (short)f2bf_u(v[e] - bf2f(hb));
      }
#pragma unroll
      for (int m = 0; m < 4; ++m) {
        acc[m][0] = __builtin_amdgcn_mfma_f32_16x16x32_bf16(a_ih[m][kt], xhi, acc[m][0], 0, 0, 0);
        acc[m][1] = __builtin_amdgcn_mfma_f32_16x16x32_bf16(a_ih[m][kt], xlo, acc[m][1], 0, 0, 0);
      }
    }

    if (t > 0) {
      // ---- cheap detect: poll 32 per-wave flags (WAR-safety requires all) ----
      {
        const unsigned* fp = fbase + (l & 31);
        for (;;) {
          unsigned f = __hip_atomic_load(fp, __ATOMIC_RELAXED, __HIP_MEMORY_SCOPE_AGENT);
          if (__all(f >= (unsigned)t)) break;
        }
      }
      __builtin_amdgcn_fence(__ATOMIC_ACQUIRE, "workgroup");
      __builtin_amdgcn_sched_barrier(0);

      // ---- quarter load + x(t+1) issue; validate tags; rare retry ----
      u32x4 qh[4], ql[4];
      const unsigned short* phh = hp + (size_t)b * H_ + w * 128 + lk * 8;
      const unsigned short* pll = phh + (size_t)(B_ * H_);
      HLOADQ(qh[0], phh, 0);   HLOADQ(qh[1], phh, 64);
      HLOADQ(qh[2], phh, 128); HLOADQ(qh[3], phh, 192);
      HLOADQ(ql[0], pll, 0);   HLOADQ(ql[1], pll, 64);
      HLOADQ(ql[2], pll, 128); HLOADQ(ql[3], pll, 192);
      {
        const int tn = (t + 1 < T_) ? t + 1 : t;
        const float* xb = xrow + tn * I_ + lk * 8;
        XLOADQ(xf0, xb, 0);   XLOADQ(xf1, xb, 16);
        XLOADQ(xf2, xb, 128); XLOADQ(xf3, xb, 144);
      }
      WAITV(4);   // 8 h-quarter loads done; 4 x loads in flight

      const unsigned tlo = (unsigned)(t & 3);
      const unsigned thi = (unsigned)((t >> 2) & 3);
      for (;;) {
        unsigned bad = 0;
#pragma unroll
        for (int i = 0; i < 4; ++i) {
          bad |= (qh[i].x ^ tlo) | (qh[i].z ^ thi)
               | (ql[i].x ^ tlo) | (ql[i].z ^ thi);
        }
        bad &= 3u;
        if (__all(bad == 0)) break;
        // rare: flag overtook data — reload the quarter
        HLOADQ(qh[0], phh, 0);   HLOADQ(qh[1], phh, 64);
        HLOADQ(qh[2], phh, 128); HLOADQ(qh[3], phh, 192);
        HLOADQ(ql[0], pll, 0);   HLOADQ(ql[1], pll, 64);
        HLOADQ(ql[2], pll, 128); HLOADQ(ql[3], pll, 192);
        WAITV(0);
      }
      __builtin_amdgcn_sched_barrier(0);

      // ---- stage into swizzled LDS ----
#pragma unroll
      for (int i = 0; i < 4; ++i) {
        *(u32x4*)&hldsF[HOFS(0, l16, 4 * w + i)] = qh[i];
        *(u32x4*)&hldsF[HOFS(1, l16, 4 * w + i)] = ql[i];
      }
      __syncthreads();

      // ---- h recurrence: fragments from LDS ----
#pragma unroll
      for (int kt = 0; kt < 16; ++kt) {
        short8 fh = *(const short8*)&hldsF[HOFS(0, l16, kt)];
        short8 fl = *(const short8*)&hldsF[HOFS(1, l16, kt)];
#pragma unroll
        for (int m = 0; m < 4; ++m) {
          acc[m][0] = __builtin_amdgcn_mfma_f32_16x16x32_bf16(a_hh[m][kt], fh, acc[m][0], 0, 0, 0);
          acc[m][1] = __builtin_amdgcn_mfma_f32_16x16x32_bf16(a_hh[m][kt], fl, acc[m][1], 0, 0, 0);
        }
      }
    } else {
      // t=0: no h term; just issue x(1) prefetch
      const float* xb = xrow + I_ + lk * 8;
      XLOADQ(xf0, xb, 0);   XLOADQ(xf1, xb, 16);
      XLOADQ(xf2, xb, 128); XLOADQ(xf3, xb, 144);
    }

    // ---- pointwise + pack; lane lk==0 injects epoch tags (pre-transpose,
    //      these words land at post-transpose m==0 positions = granule
    //      ushort[0]/ushort[4]); hi-tag compensated through lo ----
    const unsigned tgp = (unsigned)((t + 1) & 15);
    float p = 0.f;
    unsigned wd[4];           // packed (hi | lo<<16) per m
#pragma unroll
    for (int m = 0; m < 4; ++m) {
      float gi = sigm(acc[m][0].x + acc[m][1].x + bias[m][0]);
      float gf = sigm(acc[m][0].y + acc[m][1].y + bias[m][1]);
      float gg = tanh_(acc[m][0].z + acc[m][1].z + bias[m][2]);
      float go = sigm(acc[m][0].w + acc[m][1].w + bias[m][3]);
      c[m] = gf * c[m] + gi * gg;
      float hv = go * tanh_(c[m]);
      p += hv * who[m];
      unsigned tb = (m & 1) ? (tgp >> 2) : (tgp & 3u);
      unsigned hb = f2bf_u(hv);
      if (lk == 0) hb = (hb & ~3u) | tb;            // tagged hi
      unsigned lo = f2bf_u(hv - bf2f(hb));          // lo compensates tag
      if (lk == 0) lo = (lo & ~3u) | tb;            // tagged lo (2^-17|h|)
      wd[m] = hb | (lo << 16);
    }

    // ---- in-register 4x4 transpose across lk (lanes ^16, ^32) ----
    {
      unsigned r0[4], r1[4];
#pragma unroll
      for (int m = 0; m < 4; ++m) r0[m] = __shfl_xor(wd[m], 16);
#pragma unroll
      for (int m = 0; m < 4; ++m) if ((m ^ lk) & 1) wd[m] = r0[m ^ 1];
#pragma unroll
      for (int m = 0; m < 4; ++m) r1[m] = __shfl_xor(wd[m], 32);
#pragma unroll
      for (int m = 0; m < 4; ++m) if ((m ^ lk) & 2) wd[m] = r1[m ^ 2];
    }

    // ---- publish (fire-and-forget): data stores then flag, NO ack ----
    {
      unsigned hi01 = (wd[0] & 0xffffu) | (wd[1] << 16);
      unsigned hi23 = (wd[2] & 0xffffu) | (wd[3] << 16);
      unsigned lo01 = (wd[0] >> 16) | (wd[1] & 0xffff0000u);
      unsigned lo23 = (wd[2] >> 16) | (wd[3] & 0xffff0000u);
      unsigned long long hiq = (unsigned long long)hi01 | ((unsigned long long)hi23 << 32);
      unsigned long long loq = (unsigned long long)lo01 | ((unsigned long long)lo23 << 32);
      unsigned short* ph = hn + (size_t)b * H_ + jg * 64 + w * 16 + lk * 4;
      HSTORED2(ph, hiq);
      HSTORED2(ph + B_ * H_, loq);
    }
    if (l == 0)
      __hip_atomic_store(myflag, (unsigned)(t + 1),
                         __ATOMIC_RELAXED, __HIP_MEMORY_SCOPE_AGENT);

    // ---- projection partial: per-jg plane, 4-way contention only ----
    p += __shfl_xor(p, 16);
    p += __shfl_xor(p, 32);          // sum over this wave's 16 j
    if (l < 16) atomicAdd(part + ((size_t)jg * B_ + b) * T_ + t, p);
  }
#undef HOFS
}

__global__ __launch_bounds__(256) void reduce_out(const float* __restrict__ part,
                                                  const float* __restrict__ b_ho,
                                                  float* __restrict__ out) {
  int i = blockIdx.x * blockDim.x + threadIdx.x;
  if (i < B_ * T_) {
    float s = b_ho[0];
#pragma unroll
    for (int g = 0; g < 8; ++g) s += part[(size_t)g * B_ * T_ + i];
    out[i] = s;
  }
}

extern "C" void kernel_launch(void* const* d_in, const int* in_sizes, int n_in,
                              void* d_out, int out_size, void* d_ws, size_t ws_size,
                              hipStream_t stream) {
  (void)in_sizes; (void)n_in; (void)out_size; (void)ws_size;
  const float* x   = (const float*)d_in[0];
  const float* Wih = (const float*)d_in[1];
  const float* Whh = (const float*)d_in[2];
  const float* bih = (const float*)d_in[3];
  const float* bhh = (const float*)d_in[4];
  const float* Who = (const float*)d_in[5];
  const float* bho = (const float*)d_in[6];
  float* out = (float*)d_out;

  // ws: hbuf 512KB | part 1MB (8 planes) | flags 1KB
  unsigned short* hbuf = (unsigned short*)d_ws;
  const size_t hbytes = (size_t)2 * 2 * B_ * H_ * sizeof(unsigned short);
  float* part = (float*)((char*)d_ws + hbytes);
  const size_t pbytes = (size_t)8 * B_ * T_ * sizeof(float);
  unsigned* flags = (unsigned*)((char*)d_ws + hbytes + pbytes);

  // zero partials + flags (h slots written-before-read; stale tags rejected)
  hipMemsetAsync((char*)d_ws + hbytes, 0, pbytes + 8 * 32 * sizeof(unsigned), stream);

  lstm_kernel<<<dim3(64), dim3(256), 0, stream>>>(x, Wih, Whh, bih, bhh, Who,
                                                  part, hbuf, flags);
  reduce_out<<<(B_ * T_ + 255) / 256, 256, 0, stream>>>(part, bho, out);
}